// Round 2
// baseline (275697.510 us; speedup 1.0000x reference)
//
#include <hip/hip_runtime.h>

#define BB 32
#define TT 512
#define HH 1024
#define S4 (TT*HH/4)          // f4 stride between batch rows in any [B,T,H] seq

typedef const float4* __restrict__ cf4p;

__device__ __forceinline__ float sigmoidf_(float x) { return 1.0f / (1.0f + __expf(-x)); }

__device__ __forceinline__ void loadW8(float4 (&w8)[8], cf4p Wm, const int (&roff)[8], int colf4) {
  #pragma unroll
  for (int m = 0; m < 8; ++m) w8[m] = Wm[roff[m] + colf4];
}
__device__ __forceinline__ void loadX4(float4 (&x4)[4], const float4* lbuf, const int (&xbase)[4], int xo) {
  #pragma unroll
  for (int q = 0; q < 4; ++q) x4[q] = lbuf[xbase[q] + xo];
}
__device__ __forceinline__ void fma128(float (&acc)[4][8], const float4 (&x4)[4], const float4 (&w8)[8]) {
  #pragma unroll
  for (int q = 0; q < 4; ++q)
    #pragma unroll
    for (int m = 0; m < 8; ++m) {
      float a = acc[q][m];
      a = fmaf(x4[q].x, w8[m].x, a);
      a = fmaf(x4[q].y, w8[m].y, a);
      a = fmaf(x4[q].z, w8[m].z, a);
      a = fmaf(x4[q].w, w8[m].w, a);
      acc[q][m] = a;
    }
}

// One pipelined step: unit u = (layer<<1)|dir.  layer0 does time s, layer1 does its step s-1.
// Block: 64 gate-rows (16 j x 4 gates) x 32 batch x K=2048, 8 waves K-split (256 K each).
__global__ __launch_bounds__(512, 2)
void lstm_mega(const float* __restrict__ x,
               const float* __restrict__ WihF, const float* __restrict__ WhhF, const float* __restrict__ bF,
               const float* __restrict__ WihB, const float* __restrict__ WhhB, const float* __restrict__ bB,
               float* __restrict__ sf0, float* __restrict__ sb0,   // layer0 out seqs [B,T,H]
               float* __restrict__ fwd, float* __restrict__ bwd,   // layer1 out seqs [B,T,H]
               float* __restrict__ cws,                            // 4 * [H][B] c-state
               int s)
{
  const int u = blockIdx.y;
  const int layer = u >> 1, dir = u & 1;

  int t; bool first, active;
  if (layer == 0) { active = (s < TT); t = dir ? (TT-1-s) : s; first = (s == 0); }
  else            { active = (s >= 1); t = dir ? (TT-s)   : s-1; first = (s == 1); }
  if (!active) return;
  // h_prev time index; clamped to a valid in-bounds value when first (never loaded then)
  const int th = first ? t : (dir ? t+1 : t-1);

  const float* Wih  = (dir ? WihB : WihF) + (size_t)layer*4*HH*HH;
  const float* Whh  = (dir ? WhhB : WhhF) + (size_t)layer*4*HH*HH;
  const float* bias = (dir ? bB   : bF)   + (size_t)layer*4*HH;

  const float* xsq = (layer == 0) ? x : (dir ? sb0 : sf0);
  float*       hsq = (layer == 0) ? (dir ? sb0 : sf0) : (dir ? bwd : fwd);

  cf4p Xp4 = (cf4p)(xsq + (size_t)t  * HH);   // + b*S4 + col
  cf4p Hp4 = (cf4p)(hsq + (size_t)th * HH);
  float* cbuf = cws + (size_t)u * BB * HH;    // [j][b]

  const int tid  = threadIdx.x;
  const int w    = tid >> 6, lane = tid & 63;
  const int bg   = lane & 7, rg = lane >> 3;
  const int j0   = blockIdx.x * 16;

  __shared__ __align__(16) float lds[16384];  // 64 KB: buf0 [0,8192) floats, buf1 [8192,16384)
  float4* l4 = (float4*)lds;

  // per-lane W row offsets (f4 units). rows r = rg*8+m ; canonical: gate g=r>>4, jj=r&15
  int roff[8];
  #pragma unroll
  for (int m = 0; m < 8; ++m) {
    const int r = rg*8 + m;
    roff[m] = ((r >> 4)*HH + j0 + (r & 15)) * (HH/4);
  }
  // X lds bases: idx = b*64 + w*8 + ((w*8+it)^bg low bits) , b = bg*4+q
  int xbase[4];
  #pragma unroll
  for (int q = 0; q < 4; ++q) xbase[q] = (bg*4 + q)*64 + w*8;

  float acc[4][8];
  #pragma unroll
  for (int q = 0; q < 4; ++q)
    #pragma unroll
    for (int m = 0; m < 8; ++m) acc[q][m] = 0.f;

  // ---------- staging (32 rows x 256 floats per super-chunk, XOR-swizzled) ----------
  const int sbw = tid >> 6;      // staging row sub-index
  const int kq  = tid & 63;      // f4 col within chunk
  float4 g[4];

  auto stageload = [&](int sc) {
    const bool ish = (sc >= 4);
    const int colb = (ish ? sc-4 : sc) * 64;
    if (ish && first) {
      // uniform branch: no h_prev load is ever formed on the first step
      #pragma unroll
      for (int i = 0; i < 4; ++i) g[i] = make_float4(0.f, 0.f, 0.f, 0.f);
    } else {
      cf4p src = ish ? Hp4 : Xp4;
      #pragma unroll
      for (int i = 0; i < 4; ++i) {
        const int b = i*8 + sbw;
        g[i] = src[b*S4 + colb + kq];
      }
    }
  };
  auto stagewrite = [&](int bufsel) {
    float4* d = l4 + bufsel*2048;
    #pragma unroll
    for (int i = 0; i < 4; ++i) {
      const int b = i*8 + sbw;
      d[b*64 + (kq ^ (b >> 2))] = g[i];
    }
  };

  // prologue: super-chunk 0 -> buf0
  stageload(0);
  stagewrite(0);
  __syncthreads();

  cf4p W4a = (cf4p)Wih;
  cf4p W4b = (cf4p)Whh;
  float4 wa[8], wb[8], xa[4], xb[4];
  loadW8(wa, W4a, roff, w*8);
  loadX4(xa, l4, xbase, bg ^ 0);

  for (int sc = 0; sc < 8; ++sc) {
    const float4* lbuf = l4 + (sc & 1)*2048;
    cf4p Wm = (sc < 4) ? W4a : W4b;
    const int cb = (sc & 3)*64 + w*8;
    const bool more = (sc < 7);
    if (more) stageload(sc+1);             // T14: issue next-chunk loads before compute
    #pragma unroll
    for (int ith = 0; ith < 4; ++ith) {
      const int it1 = 2*ith + 1;
      loadX4(xb, lbuf, xbase, bg ^ it1);
      loadW8(wb, Wm, roff, cb + it1);
      fma128(acc, xa, wa);
      if (ith < 3) {
        loadX4(xa, lbuf, xbase, bg ^ (it1+1));
        loadW8(wa, Wm, roff, cb + it1 + 1);
      }
      fma128(acc, xb, wb);
    }
    if (more) stagewrite((sc+1) & 1);
    __syncthreads();
    if (more) {
      const float4* lb2 = l4 + ((sc+1) & 1)*2048;
      cf4p Wm2 = (sc+1 < 4) ? W4a : W4b;
      loadX4(xa, lb2, xbase, bg ^ 0);
      loadW8(wa, Wm2, roff, ((sc+1) & 3)*64 + w*8);
    }
  }

  // ---------- cross-wave K reduction: 8 slots x 2048 floats = exactly 64 KB, ONE sync ----------
  {
    float4* P = (float4*)(lds + w*2048);
    #pragma unroll
    for (int m = 0; m < 8; ++m)
      P[(rg*8 + m)*8 + bg] = make_float4(acc[0][m], acc[1][m], acc[2][m], acc[3][m]);
  }
  __syncthreads();

  float sums[4];
  #pragma unroll
  for (int i = 0; i < 4; ++i) {
    const int e = tid + i*512;
    float s0 = lds[e]          + lds[2048  + e];
    float s1 = lds[4096  + e]  + lds[6144  + e];
    float s2 = lds[8192  + e]  + lds[10240 + e];
    float s3 = lds[12288 + e]  + lds[14336 + e];
    sums[i] = (s0 + s1) + (s2 + s3);
  }

  // ---------- elementwise LSTM cell: thread = (jj = tid>>5, b = tid&31), sums[i] = gate i ----------
  const int jj = tid >> 5, b = tid & 31, j = j0 + jj;
  const float gi = sums[0] + bias[j];
  const float gf = sums[1] + bias[HH   + j];
  const float gg = sums[2] + bias[2*HH + j];
  const float go = sums[3] + bias[3*HH + j];
  const float ig = sigmoidf_(gi), fg = sigmoidf_(gf);
  const float gv = tanhf(gg),     og = sigmoidf_(go);
  const float cold = first ? 0.f : cbuf[j*BB + b];
  const float cn = fg*cold + ig*gv;
  const float hv = og * tanhf(cn);
  cbuf[j*BB + b] = cn;                       // [j][b] layout -> coalesced

  // coalesced f4 store of h via small LDS transpose
  __syncthreads();
  lds[jj*33 + b] = hv;
  __syncthreads();
  if (tid < 128) {
    const int b2 = tid >> 2, f = tid & 3;
    const float4 o4 = make_float4(lds[(f*4+0)*33 + b2], lds[(f*4+1)*33 + b2],
                                  lds[(f*4+2)*33 + b2], lds[(f*4+3)*33 + b2]);
    ((float4*)hsq)[ ((t*HH) >> 2) + b2*S4 + (j0 >> 2) + f ] = o4;
  }
}

// out[b,t,0:H] = fwd, out[b,t,H:2H] = bwd
__global__ __launch_bounds__(256)
void concat_kernel(const float4* __restrict__ fwd, const float4* __restrict__ bwd,
                   float4* __restrict__ out) {
  const int i = blockIdx.x * blockDim.x + threadIdx.x;   // over B*T*H/4
  if (i >= BB*TT*HH/4) return;
  const int row = i >> 8;     // b*T + t   (H/4 = 256)
  const int col = i & 255;
  out[(size_t)row*512 + col]       = fwd[i];
  out[(size_t)row*512 + 256 + col] = bwd[i];
}

extern "C" void kernel_launch(void* const* d_in, const int* in_sizes, int n_in,
                              void* d_out, int out_size, void* d_ws, size_t ws_size,
                              hipStream_t stream) {
  const float* x    = (const float*)d_in[0];
  const float* WihF = (const float*)d_in[1];
  const float* WhhF = (const float*)d_in[2];
  const float* bF   = (const float*)d_in[3];
  const float* WihB = (const float*)d_in[4];
  const float* WhhB = (const float*)d_in[5];
  const float* bB   = (const float*)d_in[6];

  float* out = (float*)d_out;
  // layer0 staging seqs live in the final-out region (overwritten by concat at the end);
  // fwd/bwd are required outputs and double as layer1 h-state storage.
  float* sf0 = out;
  float* sb0 = out + (size_t)BB*TT*HH;
  float* fwd = out + (size_t)BB*TT*2*HH;
  float* bwd = fwd + (size_t)BB*TT*HH;
  float* cws = (float*)d_ws;                 // 4 * B*H c-state, [j][b] per unit

  dim3 grid(HH/16, 4), block(512);
  for (int s = 0; s <= TT; ++s)
    lstm_mega<<<grid, block, 0, stream>>>(x, WihF, WhhF, bF, WihB, WhhB, bB,
                                          sf0, sb0, fwd, bwd, cws, s);

  concat_kernel<<<(BB*TT*HH/4 + 255)/256, 256, 0, stream>>>(
      (const float4*)fwd, (const float4*)bwd, (float4*)out);
}